// Round 2
// baseline (1315.697 us; speedup 1.0000x reference)
//
#include <hip/hip_runtime.h>

typedef __bf16 bf16_t;
typedef __attribute__((ext_vector_type(8))) __bf16 bf16x8;
typedef __attribute__((ext_vector_type(4))) float f32x4;
typedef unsigned short u16;
typedef unsigned int u32;

#define TC 256
#define NCHUNK 4
#define LDA 264   // 256 + 8 bf16 pad (16B) -> breaks 16-way bank conflicts, keeps 16B align
#define LDB 40    // 32 + 8 pad

// ws layout (bytes), total ~72.8 MB:
//   xg   @ 0         : 65536*512*2 = 67,108,864   (bf16 xg chunk [B*TC, 512])
//   embb @ 67108864  : 10000*256*2 =  5,120,000   (bf16 embedding table)
//   wkt  @ 72228864  : 512*256*2   =    262,144   (bf16 Wk transposed [N][K])
//   hst  @ 72491008  : 256*128*4   =    131,072   (h carry between chunks)
//   cst  @ 72622080  : 256*128*4   =    131,072   (c carry between chunks)

__global__ __launch_bounds__(256) void k_cvt_emb(const float* __restrict__ e,
                                                 u16* __restrict__ o, int n) {
  int i = blockIdx.x * 256 + threadIdx.x;
  if (i < n) o[i] = __builtin_bit_cast(u16, (bf16_t)e[i]);
}

// WkT[n][k] = Wk[k][n]  (Wk is [256][512] row-major)
__global__ __launch_bounds__(256) void k_wkt(const float* __restrict__ wk,
                                             u16* __restrict__ o) {
  int i = blockIdx.x * 256 + threadIdx.x;  // 131072 total
  int k = i & 255, n = i >> 8;
  o[i] = __builtin_bit_cast(u16, (bf16_t)wk[k * 512 + n]);
}

// xg[m, 0..511] = emb[x[g(m)]] @ Wk + bias, bf16 out. Tile: 64 rows x 512 cols per wg.
// Wave wv covers all 64 rows x cols [128*wv, 128*wv+128). MFMA 16x16x32 bf16.
// Verified layouts (m89/m91): A[m=lane&15][k=quad*8+j]; B[k=quad*8+j][n=lane&15];
// C/D: col=lane&15, row=quad*4+reg.
__global__ __launch_bounds__(256) void k_xgemm(
    const int* __restrict__ x, const u16* __restrict__ embb,
    const u16* __restrict__ wkt, const float* __restrict__ bias,
    u16* __restrict__ xg, int t0) {
  __shared__ u16 Al[64 * LDA];
  __shared__ u16 Bl[512 * LDB];
  __shared__ float biasl[512];
  const int tid = threadIdx.x;
  const int m0 = blockIdx.x * 64;
  const int bb = m0 >> 8;        // batch row (64 | TC so single b per wg)
  const int tl0 = m0 & (TC - 1); // t offset within chunk

  // stage A: 64 gathered rows x 256 bf16
  {
    const int ar = tid >> 5;          // 0..7
    const int c8 = (tid & 31) * 8;    // 0..248
#pragma unroll
    for (int p = 0; p < 8; ++p) {
      int r = p * 8 + ar;
      int g = bb * 1024 + t0 + tl0 + r;
      int idx = x[g];
      *(uint4*)&Al[r * LDA + c8] = *(const uint4*)&embb[idx * 256 + c8];
    }
    biasl[tid] = bias[tid];
    biasl[tid + 256] = bias[tid + 256];
  }

  const int wv = tid >> 6, lane = tid & 63;
  const int l16 = lane & 15, quad = lane >> 4;
  f32x4 zero = {0.f, 0.f, 0.f, 0.f};
  f32x4 acc[4][8];
#pragma unroll
  for (int mt = 0; mt < 4; ++mt)
#pragma unroll
    for (int nt = 0; nt < 8; ++nt) acc[mt][nt] = zero;

  for (int kt = 0; kt < 8; ++kt) {
    __syncthreads();  // protect Bl from previous k-step readers (covers A on kt=0)
    // stage B slice: [512 n][32 k] bf16
#pragma unroll
    for (int q8 = 0; q8 < 8; ++q8) {
      int c = q8 * 256 + tid;
      int rn = c >> 2, q = c & 3;
      *(uint4*)&Bl[rn * LDB + q * 8] = *(const uint4*)&wkt[rn * 256 + kt * 32 + q * 8];
    }
    __syncthreads();
    bf16x8 a[4];
#pragma unroll
    for (int mt = 0; mt < 4; ++mt)
      a[mt] = *(const bf16x8*)&Al[(mt * 16 + l16) * LDA + kt * 32 + quad * 8];
#pragma unroll
    for (int nt = 0; nt < 8; ++nt) {
      bf16x8 bfr = *(const bf16x8*)&Bl[(wv * 128 + nt * 16 + l16) * LDB + quad * 8];
#pragma unroll
      for (int mt = 0; mt < 4; ++mt)
        acc[mt][nt] =
            __builtin_amdgcn_mfma_f32_16x16x32_bf16(a[mt], bfr, acc[mt][nt], 0, 0, 0);
    }
  }

  // epilogue: + bias, cvt bf16, store
#pragma unroll
  for (int nt = 0; nt < 8; ++nt) {
    int col = wv * 128 + nt * 16 + l16;
    float bv = biasl[col];
#pragma unroll
    for (int mt = 0; mt < 4; ++mt) {
#pragma unroll
      for (int r = 0; r < 4; ++r) {
        int m = m0 + mt * 16 + quad * 4 + r;
        float v = acc[mt][nt][r] + bv;
        xg[m * 512 + col] = __builtin_bit_cast(u16, (bf16_t)v);
      }
    }
  }
}

// One wg (512 threads) per batch row; Wr column cached in 128 VGPRs/thread.
// z = xg_t + h @ Wr; gates i,f,c,o; c = sig(zf)*c + sig(zi)*relu(zc); h = sig(zo)*relu(c)
__global__ __launch_bounds__(512) void k_scan(
    const u16* __restrict__ xg, const float* __restrict__ Wr,
    const float* __restrict__ Wd, const float* __restrict__ bd,
    float* __restrict__ hst, float* __restrict__ cst,
    float* __restrict__ out, int chunk) {
  const int b = blockIdx.x;
  const int col = threadIdx.x;
  float wr[128];
#pragma unroll
  for (int k = 0; k < 128; ++k) wr[k] = Wr[k * 512 + col];  // coalesced per k

  __shared__ float h[128];
  __shared__ float zb[512];
  float c = 0.f;
  if (col < 128) {
    float hv = 0.f;
    if (chunk != 0) {
      hv = hst[b * 128 + col];
      c = cst[b * 128 + col];
    }
    h[col] = hv;
  }
  const u16* xgp = xg + (size_t)b * TC * 512 + col;
  u16 xraw = xgp[0];
  __syncthreads();

  for (int t = 0; t < TC; ++t) {
    float xv = __builtin_bit_cast(float, (u32)xraw << 16);
    int tn = (t < TC - 1) ? t + 1 : t;
    u16 xnext = xgp[(size_t)tn * 512];  // prefetch, used next iter
    // 4 independent FMA chains (hide 4-cyc dep latency); h reads broadcast b128
    float a0 = xv, a1 = 0.f, a2 = 0.f, a3 = 0.f;
#pragma unroll
    for (int k4 = 0; k4 < 32; ++k4) {
      f32x4 h4 = *(const f32x4*)&h[k4 * 4];
      a0 += h4[0] * wr[k4 * 4 + 0];
      a1 += h4[1] * wr[k4 * 4 + 1];
      a2 += h4[2] * wr[k4 * 4 + 2];
      a3 += h4[3] * wr[k4 * 4 + 3];
    }
    zb[col] = (a0 + a1) + (a2 + a3);
    __syncthreads();
    if (col < 128) {
      float zi = zb[col], zf = zb[col + 128], zc = zb[col + 256], zo = zb[col + 384];
      float ig = 1.f / (1.f + __expf(-zi));
      float fg = 1.f / (1.f + __expf(-zf));
      float gg = fmaxf(zc, 0.f);
      float og = 1.f / (1.f + __expf(-zo));
      c = fg * c + ig * gg;
      h[col] = og * fmaxf(c, 0.f);
    }
    xraw = xnext;
    __syncthreads();
  }

  if (chunk != NCHUNK - 1) {
    if (col < 128) {
      hst[b * 128 + col] = h[col];
      cst[b * 128 + col] = c;
    }
  } else if (col < 2) {
    float o = bd[col];
    for (int k = 0; k < 128; ++k) o += h[k] * Wd[k * 2 + col];
    out[b * 2 + col] = o;
  }
}

extern "C" void kernel_launch(void* const* d_in, const int* in_sizes, int n_in,
                              void* d_out, int out_size, void* d_ws, size_t ws_size,
                              hipStream_t stream) {
  const int* x = (const int*)d_in[0];
  const float* emb = (const float*)d_in[1];
  const float* Wk = (const float*)d_in[2];
  const float* Wr = (const float*)d_in[3];
  const float* bias = (const float*)d_in[4];
  const float* Wd = (const float*)d_in[5];
  const float* bd = (const float*)d_in[6];
  float* out = (float*)d_out;
  char* ws = (char*)d_ws;
  u16* xg = (u16*)(ws);
  u16* embb = (u16*)(ws + 67108864);
  u16* wkt = (u16*)(ws + 72228864);
  float* hst = (float*)(ws + 72491008);
  float* cst = (float*)(ws + 72622080);

  k_cvt_emb<<<10000, 256, 0, stream>>>(emb, embb, 2560000);
  k_wkt<<<512, 256, 0, stream>>>(Wk, wkt);
  for (int chunk = 0; chunk < NCHUNK; ++chunk) {
    k_xgemm<<<1024, 256, 0, stream>>>(x, embb, wkt, bias, xg, chunk * TC);
    k_scan<<<256, 512, 0, stream>>>(xg, Wr, Wd, bd, hst, cst, out, chunk);
  }
}

// Round 3
// 1026.545 us; speedup vs baseline: 1.2817x; 1.2817x over previous
//
#include <hip/hip_runtime.h>

typedef __bf16 bf16_t;
typedef __attribute__((ext_vector_type(8))) __bf16 bf16x8;
typedef __attribute__((ext_vector_type(4))) float f32x4;
typedef unsigned short u16;
typedef unsigned int u32;
typedef unsigned long long u64;

#define TC 256
#define NCHUNK 4
#define LDA 264   // 256 + 8 bf16 pad
#define LDB 40    // 32 + 8 pad

// ws layout (bytes), total ~72.8 MB:
//   xg2  @ 0         : 16*256*8192*2 = 67,108,864  (bf16 xg chunk, scan-tiled layout)
//   embb @ 67108864  : 10000*256*2   =  5,120,000
//   wkt  @ 72228864  : 512*256*2     =    262,144
//   hst  @ 72491008  : 16*128*16*4   =    131,072  (f32 h carry, [g][u][row16])
//   cst  @ 72622080  : 16*128*16*4   =    131,072  (f32 c carry)
//
// xg2 layout (u16 units): off = ((g*256 + t)*8192) + tile*256 + c16*16 + row16
//   g = b>>4 (scan wg), row16 = b&15, t = chunk-local step, tile = col>>4, c16 = col&15.
//   Scan lane (w,quad,l16) reads b64 = rows quad*4..+3 for col 16w+l16+128j, tile w+8j.

static __device__ __forceinline__ u16 bf16bits(float v) {
  return __builtin_bit_cast(u16, (bf16_t)v);
}
static __device__ __forceinline__ float bf16f(u16 v) {
  return __builtin_bit_cast(float, (u32)v << 16);
}

__global__ __launch_bounds__(256) void k_cvt_emb(const float* __restrict__ e,
                                                 u16* __restrict__ o, int n) {
  int i = blockIdx.x * 256 + threadIdx.x;
  if (i < n) o[i] = bf16bits(e[i]);
}

// WkT[n][k] = Wk[k][n]  (Wk is [256][512] row-major)
__global__ __launch_bounds__(256) void k_wkt(const float* __restrict__ wk,
                                             u16* __restrict__ o) {
  int i = blockIdx.x * 256 + threadIdx.x;  // 131072 total
  int k = i & 255, n = i >> 8;
  o[i] = bf16bits(wk[k * 512 + n]);
}

// xg2[...] = emb[x[...]] @ Wk + bias, bf16, scan-tiled layout.
// wg = (gg, tb): 64 rows = 16 batch rows (b=16gg+row16) x 4 steps (t=tb*4+tq).
// local row lr = mt*16 + quad*4 + r ; row16 = lr&15, tq = lr>>4 (= mt).
__global__ __launch_bounds__(256) void k_xgemm(
    const int* __restrict__ x, const u16* __restrict__ embb,
    const u16* __restrict__ wkt, const float* __restrict__ bias,
    u16* __restrict__ xg, int t0) {
  __shared__ u16 Al[64 * LDA];
  __shared__ u16 Bl[512 * LDB];
  __shared__ float biasl[512];
  const int tid = threadIdx.x;
  const int gg = blockIdx.x >> 6;
  const int tb = blockIdx.x & 63;

  // stage A: 64 gathered rows x 256 bf16
  {
    const int ar = tid >> 5;          // 0..7
    const int c8 = (tid & 31) * 8;    // 0..248
#pragma unroll
    for (int p = 0; p < 8; ++p) {
      int lr = p * 8 + ar;
      int xi = (16 * gg + (lr & 15)) * 1024 + t0 + tb * 4 + (lr >> 4);
      int idx = x[xi];
      *(uint4*)&Al[lr * LDA + c8] = *(const uint4*)&embb[idx * 256 + c8];
    }
    biasl[tid] = bias[tid];
    biasl[tid + 256] = bias[tid + 256];
  }

  const int wv = tid >> 6, lane = tid & 63;
  const int l16 = lane & 15, quad = lane >> 4;
  f32x4 zero = {0.f, 0.f, 0.f, 0.f};
  f32x4 acc[4][8];
#pragma unroll
  for (int mt = 0; mt < 4; ++mt)
#pragma unroll
    for (int nt = 0; nt < 8; ++nt) acc[mt][nt] = zero;

  for (int kt = 0; kt < 8; ++kt) {
    __syncthreads();
#pragma unroll
    for (int q8 = 0; q8 < 8; ++q8) {
      int c = q8 * 256 + tid;
      int rn = c >> 2, q = c & 3;
      *(uint4*)&Bl[rn * LDB + q * 8] = *(const uint4*)&wkt[rn * 256 + kt * 32 + q * 8];
    }
    __syncthreads();
    bf16x8 a[4];
#pragma unroll
    for (int mt = 0; mt < 4; ++mt)
      a[mt] = *(const bf16x8*)&Al[(mt * 16 + l16) * LDA + kt * 32 + quad * 8];
#pragma unroll
    for (int nt = 0; nt < 8; ++nt) {
      bf16x8 bfr = *(const bf16x8*)&Bl[(wv * 128 + nt * 16 + l16) * LDB + quad * 8];
#pragma unroll
      for (int mt = 0; mt < 4; ++mt)
        acc[mt][nt] =
            __builtin_amdgcn_mfma_f32_16x16x32_bf16(a[mt], bfr, acc[mt][nt], 0, 0, 0);
    }
  }

  // epilogue: + bias, pack 4 rows (quad*4..+3) into one b64, coalesced store
  const size_t gtbase = (size_t)(gg * 256 + tb * 4) * 8192;
#pragma unroll
  for (int nt = 0; nt < 8; ++nt) {
    int col = wv * 128 + nt * 16 + l16;
    float bv = biasl[col];
    int tile = wv * 8 + nt;
#pragma unroll
    for (int mt = 0; mt < 4; ++mt) {
      u64 pk = 0;
#pragma unroll
      for (int r = 0; r < 4; ++r)
        pk |= (u64)bf16bits(acc[mt][nt][r] + bv) << (16 * r);
      size_t off = gtbase + (size_t)mt * 8192 + tile * 256 + l16 * 16 + quad * 4;
      *(u64*)&xg[off] = pk;
    }
  }
}

// MFMA scan: 16 wgs x 512 threads; wg g owns batch rows [16g,16g+16).
// Wave w (0..7): tiles {w, w+8, w+16, w+24} = gates i,f,c,o of unit col u=16w+l16.
// Lane state: c for (rows quad*4..+3, col u). Wr B-frags resident in VGPRs.
// h double-buffered in LDS (bf16, row stride 136), one barrier/step.
__global__ __launch_bounds__(512) void k_scan(
    const u16* __restrict__ xg, const float* __restrict__ Wr,
    const float* __restrict__ Wd, const float* __restrict__ bd,
    float* __restrict__ hstf, float* __restrict__ cstf,
    float* __restrict__ out, int chunk) {
  const int g = blockIdx.x;
  const int tid = threadIdx.x;
  const int w = tid >> 6, lane = tid & 63;
  const int l16 = lane & 15, quad = lane >> 4;
  const int u = 16 * w + l16;

  __shared__ u16 hbuf[2][16 * 136];

  // preload Wr fragments: wf[j][kt][jj] = bf16(Wr[kt*32+quad*8+jj][u+128j])
  bf16x8 wf[4][4];
#pragma unroll
  for (int j = 0; j < 4; ++j)
#pragma unroll
    for (int kt = 0; kt < 4; ++kt) {
      const float* p = Wr + (kt * 32 + quad * 8) * 512 + u + 128 * j;
#pragma unroll
      for (int jj = 0; jj < 8; ++jj) wf[j][kt][jj] = (bf16_t)p[jj * 512];
    }

  // init h, c
  f32x4 c4 = {0.f, 0.f, 0.f, 0.f};
  if (chunk == 0) {
    for (int i = tid; i < 16 * 136; i += 512) hbuf[0][i] = 0;
  } else {
    c4 = *(const f32x4*)&cstf[(g * 128 + u) * 16 + quad * 4];
    f32x4 h4 = *(const f32x4*)&hstf[(g * 128 + u) * 16 + quad * 4];
#pragma unroll
    for (int r = 0; r < 4; ++r)
      hbuf[0][(quad * 4 + r) * 136 + u] = bf16bits(h4[r]);
  }

  const u16* xbase = xg + (size_t)g * TC * 8192;
  const int xlane = l16 * 16 + quad * 4;  // u16 offset within a tile block

  u64 xga[4], xgb[4];
#pragma unroll
  for (int j = 0; j < 4; ++j)
    xga[j] = *(const u64*)&xbase[(w + 8 * j) * 256 + xlane];
#pragma unroll
  for (int j = 0; j < 4; ++j)
    xgb[j] = *(const u64*)&xbase[8192 + (w + 8 * j) * 256 + xlane];

  __syncthreads();

  f32x4 hl = {0.f, 0.f, 0.f, 0.f};

  auto step = [&](int t, u64* xgv, int pft) {
    const u16* hb = &hbuf[t & 1][0];
    u16* hn = &hbuf[(t & 1) ^ 1][0];
    bf16x8 a[4];
#pragma unroll
    for (int kt = 0; kt < 4; ++kt)
      a[kt] = *(const bf16x8*)&hb[l16 * 136 + kt * 32 + quad * 8];
    f32x4 acc[4];
#pragma unroll
    for (int j = 0; j < 4; ++j) acc[j] = f32x4{0.f, 0.f, 0.f, 0.f};
#pragma unroll
    for (int j = 0; j < 4; ++j)
#pragma unroll
      for (int kt = 0; kt < 4; ++kt)
        acc[j] = __builtin_amdgcn_mfma_f32_16x16x32_bf16(a[kt], wf[j][kt], acc[j], 0, 0, 0);
    // consume prefetched xg, then issue next prefetch (2 steps ahead)
    float xf[4][4];
#pragma unroll
    for (int j = 0; j < 4; ++j)
#pragma unroll
      for (int r = 0; r < 4; ++r)
        xf[j][r] = bf16f((u16)(xgv[j] >> (16 * r)));
#pragma unroll
    for (int j = 0; j < 4; ++j)
      xgv[j] = *(const u64*)&xbase[(size_t)pft * 8192 + (w + 8 * j) * 256 + xlane];
    // gates (all in-lane: acc[0..3] are zi,zf,zc,zo of col u, rows quad*4+r)
#pragma unroll
    for (int r = 0; r < 4; ++r) {
      float zi = acc[0][r] + xf[0][r];
      float zf = acc[1][r] + xf[1][r];
      float zc = acc[2][r] + xf[2][r];
      float zo = acc[3][r] + xf[3][r];
      float ig = __builtin_amdgcn_rcpf(1.f + __expf(-zi));
      float fg = __builtin_amdgcn_rcpf(1.f + __expf(-zf));
      float og = __builtin_amdgcn_rcpf(1.f + __expf(-zo));
      float gg = fmaxf(zc, 0.f);
      c4[r] = fg * c4[r] + ig * gg;
      float hr = og * fmaxf(c4[r], 0.f);
      hl[r] = hr;
      hn[(quad * 4 + r) * 136 + u] = bf16bits(hr);
    }
    __syncthreads();
  };

  for (int t = 0; t < TC; t += 2) {
    int p0 = t + 2 < TC ? t + 2 : TC - 1;
    int p1 = t + 3 < TC ? t + 3 : TC - 1;
    step(t, xga, p0);
    step(t + 1, xgb, p1);
  }

  if (chunk != NCHUNK - 1) {
    *(f32x4*)&cstf[(g * 128 + u) * 16 + quad * 4] = c4;
    *(f32x4*)&hstf[(g * 128 + u) * 16 + quad * 4] = hl;
  } else if (tid < 32) {
    // final h is in hbuf[0] (t=255 wrote buf 0; barrier already passed)
    int row = tid >> 1, jo = tid & 1;
    float o = bd[jo];
    for (int k = 0; k < 128; ++k)
      o += bf16f(hbuf[0][row * 136 + k]) * Wd[k * 2 + jo];
    out[(g * 16 + row) * 2 + jo] = o;
  }
}

extern "C" void kernel_launch(void* const* d_in, const int* in_sizes, int n_in,
                              void* d_out, int out_size, void* d_ws, size_t ws_size,
                              hipStream_t stream) {
  const int* x = (const int*)d_in[0];
  const float* emb = (const float*)d_in[1];
  const float* Wk = (const float*)d_in[2];
  const float* Wr = (const float*)d_in[3];
  const float* bias = (const float*)d_in[4];
  const float* Wd = (const float*)d_in[5];
  const float* bd = (const float*)d_in[6];
  float* out = (float*)d_out;
  char* ws = (char*)d_ws;
  u16* xg = (u16*)(ws);
  u16* embb = (u16*)(ws + 67108864);
  u16* wkt = (u16*)(ws + 72228864);
  float* hst = (float*)(ws + 72491008);
  float* cst = (float*)(ws + 72622080);

  k_cvt_emb<<<10000, 256, 0, stream>>>(emb, embb, 2560000);
  k_wkt<<<512, 256, 0, stream>>>(Wk, wkt);
  for (int chunk = 0; chunk < NCHUNK; ++chunk) {
    k_xgemm<<<1024, 256, 0, stream>>>(x, embb, wkt, bias, xg, chunk * TC);
    k_scan<<<16, 512, 0, stream>>>(xg, Wr, Wd, bd, hst, cst, out, chunk);
  }
}